// Round 1
// baseline (111.135 us; speedup 1.0000x reference)
//
#include <hip/hip_runtime.h>

#define BATCH 4
#define NPTS 8192
#define SPLIT 16                    // j-dimension split per (dir,b,itile)
#define PPT 4                       // pred points per thread
#define TPB 256
#define ITILE (TPB * PPT)           // 1024 A-points per block
#define NITILES (NPTS / ITILE)      // 8
#define CHUNK (NPTS / SPLIT)        // 512 B-points staged per block

// One direction-pass block: computes, for ITILE points of side A, the partial
// min squared distance over a CHUNK slice of side B, then atomicMin-publishes.
__global__ __launch_bounds__(TPB) void chamfer_pass(
    const float* __restrict__ pred, const float* __restrict__ gt,
    unsigned* __restrict__ minbuf) {
  __shared__ float4 sB[CHUNK];      // (x, y, z, x^2+y^2+z^2) per B-point

  int blk = blockIdx.x;
  int split = blk & (SPLIT - 1);    blk >>= 4;   // SPLIT  = 16
  int itile = blk & (NITILES - 1);  blk >>= 3;   // NITILES = 8
  int b     = blk & (BATCH - 1);    blk >>= 2;   // BATCH  = 4
  int dir   = blk;                                // 0: pred->gt, 1: gt->pred

  const float* Aside = dir ? gt : pred;
  const float* Bside = dir ? pred : gt;
  const float* Ab = Aside + (size_t)b * NPTS * 3;
  const float* Bb = Bside + (size_t)b * NPTS * 3;

  int t = threadIdx.x;

  // Stage the B chunk into LDS with precomputed squared norm.
  for (int j = t; j < CHUNK; j += TPB) {
    int gj = split * CHUNK + j;
    float gx = Bb[gj * 3 + 0];
    float gy = Bb[gj * 3 + 1];
    float gz = Bb[gj * 3 + 2];
    sB[j] = make_float4(gx, gy, gz, gx * gx + gy * gy + gz * gz);
  }
  __syncthreads();

  // Load this thread's PPT A-points; fold the -2 factor into the registers.
  float px[PPT], py[PPT], pz[PPT], x2[PPT], mn[PPT];
  int ibase = itile * ITILE;
  #pragma unroll
  for (int p = 0; p < PPT; ++p) {
    int i = ibase + p * TPB + t;
    float ax = Ab[i * 3 + 0];
    float ay = Ab[i * 3 + 1];
    float az = Ab[i * 3 + 2];
    x2[p] = ax * ax + ay * ay + az * az;
    px[p] = -2.f * ax;
    py[p] = -2.f * ay;
    pz[p] = -2.f * az;
    mn[p] = 3.4e38f;
  }

  // Main loop: d = (x2 + y2) - 2*(ax*gx + ay*gy + az*gz); 5 VALU per pair.
  #pragma unroll 4
  for (int j = 0; j < CHUNK; ++j) {
    float4 g = sB[j];               // broadcast ds_read_b128, conflict-free
    #pragma unroll
    for (int p = 0; p < PPT; ++p) {
      float d = x2[p] + g.w;
      d = fmaf(px[p], g.x, d);
      d = fmaf(py[p], g.y, d);
      d = fmaf(pz[p], g.z, d);
      mn[p] = fminf(mn[p], d);
    }
  }

  // Publish: clamp (commutes with min) so bits are totally ordered as uint.
  #pragma unroll
  for (int p = 0; p < PPT; ++p) {
    int i = ibase + p * TPB + t;
    float m = fmaxf(mn[p], 0.f);
    atomicMin(&minbuf[(size_t)dir * BATCH * NPTS + (size_t)b * NPTS + i],
              __float_as_uint(m));
  }
}

// Single-block final reduction: sum all 2*B*N mins, scale by 1/(B*N).
__global__ __launch_bounds__(1024) void chamfer_reduce(
    const unsigned* __restrict__ minbuf, float* __restrict__ out) {
  const int total = 2 * BATCH * NPTS;   // 65536
  int t = threadIdx.x;
  float s = 0.f;
  const uint4* mb4 = (const uint4*)minbuf;
  for (int i = t; i < total / 4; i += 1024) {
    uint4 v = mb4[i];
    s += __uint_as_float(v.x) + __uint_as_float(v.y) +
         __uint_as_float(v.z) + __uint_as_float(v.w);
  }
  #pragma unroll
  for (int off = 32; off > 0; off >>= 1) s += __shfl_down(s, off, 64);
  __shared__ float wsum[16];
  int wave = t >> 6, lane = t & 63;
  if (lane == 0) wsum[wave] = s;
  __syncthreads();
  if (t == 0) {
    float tot = 0.f;
    #pragma unroll
    for (int w = 0; w < 16; ++w) tot += wsum[w];
    out[0] = tot / (float)(BATCH * NPTS);  // cham_x/(B*N) + cham_y/(B*M)
  }
}

extern "C" void kernel_launch(void* const* d_in, const int* in_sizes, int n_in,
                              void* d_out, int out_size, void* d_ws, size_t ws_size,
                              hipStream_t stream) {
  const float* pred = (const float*)d_in[0];
  const float* gt   = (const float*)d_in[1];
  float* out        = (float*)d_out;
  unsigned* minbuf  = (unsigned*)d_ws;   // 2*BATCH*NPTS floats = 256 KB

  // Sentinel: 0x7F7F7F7F ≈ 3.39e38f; larger (as uint) than any real distance.
  hipMemsetAsync(d_ws, 0x7F, (size_t)2 * BATCH * NPTS * sizeof(float), stream);

  dim3 grid(2 * BATCH * NITILES * SPLIT);   // 1024 blocks
  chamfer_pass<<<grid, TPB, 0, stream>>>(pred, gt, minbuf);
  chamfer_reduce<<<1, 1024, 0, stream>>>(minbuf, out);
}